// Round 4
// baseline (355.888 us; speedup 1.0000x reference)
//
#include <hip/hip_runtime.h>
#include <hip/hip_bf16.h>

#define N_NODE 50000
#define NEDGE  600000
#define NRANGE 128
#define RSZ    391       // ceil(N_NODE / NRANGE); 128*391 = 50048 >= 50000
#define CAPB   6144      // slot capacity per (rel,range): mean 4688 + ~21 sigma
#define CHUNK  4096
#define NBLK1  147       // ceil(NEDGE / CHUNK)

typedef __hip_bfloat16 bf16;
typedef __attribute__((ext_vector_type(8))) short short8;
typedef __attribute__((ext_vector_type(4))) float floatx4;

__device__ __forceinline__ short f2s(float f) {
    bf16 t = __float2bfloat16(f);
    return *(short*)&t;
}
__device__ __forceinline__ unsigned pk2(float lo, float hi) {
    return ((unsigned)(unsigned short)f2s(lo)) | (((unsigned)(unsigned short)f2s(hi)) << 16);
}
__device__ __forceinline__ void acc2(float& a, float& b, unsigned w, float m) {
    a += m * __uint_as_float(w << 16);
    b += m * __uint_as_float(w & 0xFFFF0000u);
}

// rel 0 = dd (dst=drug), 1 = gd (dst=drug), 2 = dg (dst=gene), 3 = gg (dst=gene)
// key packing: (bucket:7 << 25) | (dst_local:9 << 16) | (src:16)

// ---------- stage A: partition edges into fixed-capacity (rel,range) slots ----------
__global__ __launch_bounds__(256) void k_part(
    const int* __restrict__ d0, const int* __restrict__ s0,
    const int* __restrict__ d1, const int* __restrict__ s1,
    const int* __restrict__ d2, const int* __restrict__ s2,
    const int* __restrict__ d3, const int* __restrict__ s3,
    int* __restrict__ gcur, unsigned* __restrict__ gpart)
{
    __shared__ int hcur[NRANGE];
    __shared__ int delta[NRANGE];
    __shared__ int sc[256];
    __shared__ unsigned buf[CHUNK];
    int bid = blockIdx.x;
    int rel = bid / NBLK1;
    int c   = bid - rel * NBLK1;
    int tid = threadIdx.x;
    const int* dp = rel == 0 ? d0 : rel == 1 ? d1 : rel == 2 ? d2 : d3;
    const int* sp = rel == 0 ? s0 : rel == 1 ? s1 : rel == 2 ? s2 : s3;
    int e0 = c * CHUNK;
    int e1 = min(e0 + CHUNK, NEDGE);
    int cnt_chunk = e1 - e0;

    if (tid < NRANGE) hcur[tid] = 0;
    __syncthreads();
    for (int e = e0 + tid; e < e1; e += 256)
        atomicAdd(&hcur[dp[e] / RSZ], 1);
    __syncthreads();
    int v = (tid < NRANGE) ? hcur[tid] : 0;
    sc[tid] = v;
    __syncthreads();
    for (int d = 1; d < NRANGE; d <<= 1) {
        int t = (tid >= d && tid < NRANGE) ? sc[tid - d] : 0;
        __syncthreads();
        sc[tid] += t;
        __syncthreads();
    }
    if (tid < NRANGE) {
        int start = sc[tid] - v;
        int bg    = rel * NRANGE + tid;
        int resv  = atomicAdd(&gcur[bg], v);
        delta[tid] = bg * CAPB + resv - start;
        hcur[tid]  = start;
    }
    __syncthreads();
    for (int e = e0 + tid; e < e1; e += 256) {
        int d = dp[e];
        int b = d / RSZ;
        int p = atomicAdd(&hcur[b], 1);
        buf[p] = ((unsigned)b << 25) | ((unsigned)(d - b * RSZ) << 16) | (unsigned)sp[e];
    }
    __syncthreads();
    for (int i = tid; i < cnt_chunk; i += 256) {
        unsigned key = buf[i];
        gpart[delta[key >> 25] + i] = key;
    }
}

// ---------- stage B+C merged: per (rel,range) block -> final CSR (off + edges) ----------
__global__ __launch_bounds__(256) void k_csr(
    const unsigned* __restrict__ gpart, const int* __restrict__ gcnt,
    int* __restrict__ off, unsigned short* __restrict__ edges)
{
    __shared__ int cur[RSZ];
    __shared__ unsigned short stg[CAPB];
    __shared__ int sc[256];
    int bid = blockIdx.x;
    int rel = bid >> 7, r = bid & (NRANGE - 1);
    int tid = threadIdx.x;
    int range0 = r * RSZ;
    int RS = min(RSZ, N_NODE - range0);
    if (RS < 0) RS = 0;
    int count = gcnt[bid];
    size_t slot0 = (size_t)bid * CAPB;

    // local base: exclusive scan of this rel's 128 bucket counts up to r
    int vb = (tid < NRANGE) ? gcnt[rel * NRANGE + tid] : 0;
    sc[tid] = vb;
    __syncthreads();
    for (int d = 1; d < NRANGE; d <<= 1) {
        int t = (tid >= d && tid < NRANGE) ? sc[tid - d] : 0;
        __syncthreads();
        sc[tid] += t;
        __syncthreads();
    }
    int base = (r > 0) ? sc[r - 1] : 0;
    __syncthreads();

    for (int i = tid; i < RSZ; i += 256) cur[i] = 0;
    __syncthreads();
    for (int i = tid; i < count; i += 256)
        atomicAdd(&cur[(gpart[slot0 + i] >> 16) & 0x1FF], 1);
    __syncthreads();
    int vloc[2]; int run = 0;
#pragma unroll
    for (int j = 0; j < 2; j++) {
        int idx = tid * 2 + j;
        int x = (idx < RSZ) ? cur[idx] : 0;
        vloc[j] = x; run += x;
    }
    sc[tid] = run;
    __syncthreads();
    for (int d = 1; d < 256; d <<= 1) {
        int t = (tid >= d) ? sc[tid - d] : 0;
        __syncthreads();
        sc[tid] += t;
        __syncthreads();
    }
    int excl = sc[tid] - run;
    run = excl;
#pragma unroll
    for (int j = 0; j < 2; j++) {
        int idx = tid * 2 + j;
        if (idx < RSZ) { int x = vloc[j]; cur[idx] = run; run += x; }
    }
    __syncthreads();
    for (int i = tid; i < RS; i += 256)
        off[rel * (N_NODE + 1) + range0 + i] = base + cur[i];
    if (r == NRANGE - 1 && tid == 0) off[rel * (N_NODE + 1) + N_NODE] = NEDGE;
    __syncthreads();
    for (int i = tid; i < count; i += 256) {
        unsigned key = gpart[slot0 + i];
        int p = atomicAdd(&cur[(key >> 16) & 0x1FF], 1);
        stg[p] = (unsigned short)(key & 0xFFFFu);
    }
    __syncthreads();
    for (int i = tid; i < count; i += 256)
        edges[(size_t)rel * NEDGE + base + i] = stg[i];
}

// ---------- degree-sort of (node,half) units: hist -> suffix-scan -> scatter ----------
// unit u in [0,2N): half = u>=N (drug: rels 0+1, gene: rels 2+3). bin = min(degA+degB, 63).
// Descending order (largest-degree units first) so waves get equal-degree groups.
__global__ __launch_bounds__(512) void k_ohist(
    const int* __restrict__ off, int* __restrict__ bins)
{
    __shared__ int lb[64];
    int tid = threadIdx.x;
    if (tid < 64) lb[tid] = 0;
    __syncthreads();
    int u = blockIdx.x * 512 + tid;
    if (u < 2 * N_NODE) {
        int half = u >= N_NODE;
        int w = u - (half ? N_NODE : 0);
        const int* oA = off + (half ? 2 : 0) * (N_NODE + 1);
        const int* oB = off + (half ? 3 : 1) * (N_NODE + 1);
        int nT = (oA[w + 1] - oA[w]) + (oB[w + 1] - oB[w]);
        atomicAdd(&lb[min(nT, 63)], 1);
    }
    __syncthreads();
    if (tid < 64 && lb[tid]) atomicAdd(&bins[tid], lb[tid]);
}

__global__ void k_oscan(const int* __restrict__ bins, int* __restrict__ cursor)
{
    __shared__ int s[64];
    int t = threadIdx.x;   // 64 threads
    s[t] = bins[t];
    __syncthreads();
    int acc = 0;
    for (int b = t + 1; b < 64; b++) acc += s[b];   // suffix sum: larger bins first
    cursor[t] = acc;
}

__global__ __launch_bounds__(512) void k_oscat(
    const int* __restrict__ off, int* __restrict__ cursor, int* __restrict__ order)
{
    __shared__ int lb[64], lbase[64], lcur[64];
    int tid = threadIdx.x;
    if (tid < 64) { lb[tid] = 0; lcur[tid] = 0; }
    __syncthreads();
    int u = blockIdx.x * 512 + tid;
    int b = -1;
    if (u < 2 * N_NODE) {
        int half = u >= N_NODE;
        int w = u - (half ? N_NODE : 0);
        const int* oA = off + (half ? 2 : 0) * (N_NODE + 1);
        const int* oB = off + (half ? 3 : 1) * (N_NODE + 1);
        int nT = (oA[w + 1] - oA[w]) + (oB[w + 1] - oB[w]);
        b = min(nT, 63);
        atomicAdd(&lb[b], 1);
    }
    __syncthreads();
    if (tid < 64 && lb[tid]) lbase[tid] = atomicAdd(&cursor[tid], lb[tid]);
    __syncthreads();
    if (b >= 0) {
        int p = atomicAdd(&lcur[b], 1);
        order[lbase[b] + p] = u;
    }
}

// ---------- MFMA dual-weight GEMM pair: out(bf16) = X @ [Wa | Wb], 2 problems ----------
template <int K, int NOUT, bool AFP32>
__global__ __launch_bounds__(256) void k_gemm_pair(
    const void* __restrict__ X0, const void* __restrict__ X1,
    const float* __restrict__ Wa0, const float* __restrict__ Wb0,
    const float* __restrict__ Wa1, const float* __restrict__ Wb1,
    bf16* __restrict__ out0, bf16* __restrict__ out1, int M)
{
    constexpr int NB  = NOUT / 16;
    constexpr int KC  = K / 32;
    constexpr int NH  = NOUT / 2;
    constexpr int NBL = (NB == 8) ? 3 : 2;
    __shared__ short Wl[KC * NB * 512];

    int sel = blockIdx.y;
    const void*  X  = sel ? X1 : X0;
    const float* Wa = sel ? Wa1 : Wa0;
    const float* Wb = sel ? Wb1 : Wb0;
    bf16*        out = sel ? out1 : out0;

    int tid = threadIdx.x;
    for (int i = tid; i < KC * NB * 512; i += 256) {
        int j  = i & 7;
        int n  = (i >> 3) & 15;
        int q  = (i >> 7) & 3;
        int nb = (i >> 9) & (NB - 1);
        int kc = i >> (9 + NBL);
        int k  = kc * 32 + q * 8 + j;
        int c  = nb * 16 + n;
        float w = (c < NH) ? Wa[k * NH + c] : Wb[k * NH + (c - NH)];
        Wl[i] = f2s(w);
    }
    __syncthreads();

    int lane = tid & 63, wv = tid >> 6;
    int q = lane >> 4, lidx = lane & 15;
    int row0 = blockIdx.x * 64 + wv * 16;
    int rowA = min(row0 + lidx, M - 1);

    floatx4 acc[NB];
#pragma unroll
    for (int nb = 0; nb < NB; nb++) acc[nb] = (floatx4){0.f, 0.f, 0.f, 0.f};

#pragma unroll
    for (int kc = 0; kc < KC; kc++) {
        short8 a;
        if constexpr (AFP32) {
            const float* Xf = (const float*)X + (size_t)rowA * K + kc * 32 + q * 8;
            float4 f0 = *(const float4*)Xf;
            float4 f1 = *(const float4*)(Xf + 4);
            a[0] = f2s(f0.x); a[1] = f2s(f0.y); a[2] = f2s(f0.z); a[3] = f2s(f0.w);
            a[4] = f2s(f1.x); a[5] = f2s(f1.y); a[6] = f2s(f1.z); a[7] = f2s(f1.w);
        } else {
            a = *(const short8*)((const short*)X + (size_t)rowA * K + kc * 32 + q * 8);
        }
#pragma unroll
        for (int nb = 0; nb < NB; nb++) {
            short8 b = *(const short8*)&Wl[((kc * NB + nb) * 64 + lane) * 8];
            acc[nb] = __builtin_amdgcn_mfma_f32_16x16x32_bf16(a, b, acc[nb], 0, 0, 0);
        }
    }
#pragma unroll
    for (int nb = 0; nb < NB; nb++) {
#pragma unroll
        for (int r = 0; r < 4; r++) {
            int row = row0 + q * 4 + r;
            if (row < M)
                out[(size_t)row * NOUT + nb * 16 + lidx] = __float2bfloat16(acc[nb][r]);
        }
    }
}

// ---------- group-per-node segment accumulate (round-2 proven structure) ----------
template<int ROWU>
__device__ __forceinline__ void seg_run(
    int n, const unsigned short* __restrict__ ep, float sc,
    const unsigned* __restrict__ base, float* s)
{
    int nfull = n & ~3;
    for (int i = 0; i < nfull; i += 4) {
        int e0 = ep[i + 0];
        int e1 = ep[i + 1];
        int e2 = ep[i + 2];
        int e3 = ep[i + 3];
        uint4 w0 = *(const uint4*)(base + e0 * ROWU);
        uint4 w1 = *(const uint4*)(base + e1 * ROWU);
        uint4 w2 = *(const uint4*)(base + e2 * ROWU);
        uint4 w3 = *(const uint4*)(base + e3 * ROWU);
        acc2(s[0], s[1], w0.x, sc); acc2(s[2], s[3], w0.y, sc);
        acc2(s[4], s[5], w0.z, sc); acc2(s[6], s[7], w0.w, sc);
        acc2(s[0], s[1], w1.x, sc); acc2(s[2], s[3], w1.y, sc);
        acc2(s[4], s[5], w1.z, sc); acc2(s[6], s[7], w1.w, sc);
        acc2(s[0], s[1], w2.x, sc); acc2(s[2], s[3], w2.y, sc);
        acc2(s[4], s[5], w2.z, sc); acc2(s[6], s[7], w2.w, sc);
        acc2(s[0], s[1], w3.x, sc); acc2(s[2], s[3], w3.y, sc);
        acc2(s[4], s[5], w3.z, sc); acc2(s[6], s[7], w3.w, sc);
    }
    for (int i = nfull; i < n; i++) {
        int e = ep[i];
        uint4 w = *(const uint4*)(base + e * ROWU);
        acc2(s[0], s[1], w.x, sc); acc2(s[2], s[3], w.y, sc);
        acc2(s[4], s[5], w.z, sc); acc2(s[6], s[7], w.w, sc);
    }
}

// ---------- fused layer-1 gather: 8-lane group per node via degree-sorted order ----------
__global__ __launch_bounds__(256) void k_gather64v4(
    const bf16* __restrict__ m1, const int* __restrict__ order,
    const int* __restrict__ offA0, const unsigned short* __restrict__ eA0,
    const int* __restrict__ offB0, const unsigned short* __restrict__ eB0,
    const float* __restrict__ bias0, bf16* __restrict__ out0,
    const int* __restrict__ offA1, const unsigned short* __restrict__ eA1,
    const int* __restrict__ offB1, const unsigned short* __restrict__ eB1,
    const float* __restrict__ bias1, bf16* __restrict__ out1)
{
    int tid  = threadIdx.x;
    int gid  = blockIdx.x * 32 + (tid >> 3);   // grid exact: 3125*32 = 100000
    int lidx = tid & 7;
    int u    = order[gid];
    int half = (u >= N_NODE);
    int wid  = u - (half ? N_NODE : 0);
    const int* offA = half ? offA1 : offA0;
    const unsigned short* eA = half ? eA1 : eA0;
    const int* offB = half ? offB1 : offB0;
    const unsigned short* eB = half ? eB1 : eB0;
    const float* bias = half ? bias1 : bias0;
    bf16* out = half ? out1 : out0;

    const unsigned* base = (const unsigned*)m1 + (half ? 32 : 0) + lidx * 4;

    int begA = offA[wid], nA = offA[wid + 1] - begA;
    int begB = offB[wid], nB = offB[wid + 1] - begB;
    float ia = 1.f / (float)max(nA, 1);
    float ib = 1.f / (float)max(nB, 1);

    float s[8] = {0.f,0.f,0.f,0.f,0.f,0.f,0.f,0.f};
    seg_run<64>(nA, eA + begA, ia, base, s);
    seg_run<64>(nB, eB + begB, ib, base + N_NODE * 64, s);

    float h[8];
#pragma unroll
    for (int k = 0; k < 8; k++)
        h[k] = fmaxf(s[k] + bias[lidx * 8 + k], 0.f);
    uint4 v;
    v.x = pk2(h[0], h[1]); v.y = pk2(h[2], h[3]);
    v.z = pk2(h[4], h[5]); v.w = pk2(h[6], h[7]);
    *(uint4*)(out + (size_t)wid * 64 + lidx * 8) = v;
}

// ---------- fused layer-2 gather: 4-lane group per node via degree-sorted order ----------
__global__ __launch_bounds__(256) void k_gather32v4(
    const bf16* __restrict__ m2, const int* __restrict__ order,
    const int* __restrict__ offA0, const unsigned short* __restrict__ eA0,
    const int* __restrict__ offB0, const unsigned short* __restrict__ eB0,
    const float* __restrict__ bias0, float* __restrict__ out0,
    const int* __restrict__ offA1, const unsigned short* __restrict__ eA1,
    const int* __restrict__ offB1, const unsigned short* __restrict__ eB1,
    const float* __restrict__ bias1, float* __restrict__ out1)
{
    int tid  = threadIdx.x;
    int gid  = blockIdx.x * 64 + (tid >> 2);
    int lidx = tid & 3;
    if (gid >= 2 * N_NODE) return;
    int u    = order[gid];
    int half = (u >= N_NODE);
    int wid  = u - (half ? N_NODE : 0);
    const int* offA = half ? offA1 : offA0;
    const unsigned short* eA = half ? eA1 : eA0;
    const int* offB = half ? offB1 : offB0;
    const unsigned short* eB = half ? eB1 : eB0;
    const float* bias = half ? bias1 : bias0;
    float* out = half ? out1 : out0;

    const unsigned* base = (const unsigned*)m2 + (half ? 16 : 0) + lidx * 4;

    int begA = offA[wid], nA = offA[wid + 1] - begA;
    int begB = offB[wid], nB = offB[wid + 1] - begB;
    float ia = 1.f / (float)max(nA, 1);
    float ib = 1.f / (float)max(nB, 1);

    float s[8] = {0.f,0.f,0.f,0.f,0.f,0.f,0.f,0.f};
    seg_run<32>(nA, eA + begA, ia, base, s);
    seg_run<32>(nB, eB + begB, ib, base + N_NODE * 32, s);

    float* o = out + (size_t)wid * 32 + lidx * 8;
    float4 v0, v1;
    v0.x = s[0] + bias[lidx * 8 + 0];
    v0.y = s[1] + bias[lidx * 8 + 1];
    v0.z = s[2] + bias[lidx * 8 + 2];
    v0.w = s[3] + bias[lidx * 8 + 3];
    v1.x = s[4] + bias[lidx * 8 + 4];
    v1.y = s[5] + bias[lidx * 8 + 5];
    v1.z = s[6] + bias[lidx * 8 + 6];
    v1.w = s[7] + bias[lidx * 8 + 7];
    *(float4*)o = v0;
    *(float4*)(o + 4) = v1;
}

// ---------------- launcher ----------------
extern "C" void kernel_launch(void* const* d_in, const int* in_sizes, int n_in,
                              void* d_out, int out_size, void* d_ws, size_t ws_size,
                              hipStream_t stream)
{
    const float* xd = (const float*)d_in[0];
    const float* xg = (const float*)d_in[1];
    const int* dd_src = (const int*)d_in[2];  const int* dd_dst = (const int*)d_in[3];
    const int* dg_src = (const int*)d_in[4];  const int* dg_dst = (const int*)d_in[5];
    const int* gd_src = (const int*)d_in[6];  const int* gd_dst = (const int*)d_in[7];
    const int* gg_src = (const int*)d_in[8];  const int* gg_dst = (const int*)d_in[9];
    const float* W1dd = (const float*)d_in[10];
    const float* W1dg = (const float*)d_in[11];
    const float* W1gd = (const float*)d_in[12];
    const float* W1gg = (const float*)d_in[13];
    const float* b1d  = (const float*)d_in[14];
    const float* b1g  = (const float*)d_in[15];
    const float* W2dd = (const float*)d_in[16];
    const float* W2dg = (const float*)d_in[17];
    const float* W2gd = (const float*)d_in[18];
    const float* W2gg = (const float*)d_in[19];
    const float* b2d  = (const float*)d_in[20];
    const float* b2g  = (const float*)d_in[21];
    float* out = (float*)d_out;

    // workspace layout
    int* gcur     = (int*)d_ws;                        // 512
    int* bins     = gcur + 512;                        // 64 (order histogram)
    int* cursor   = bins + 64;                         // 64 (order cursors)
    int* off      = gcur + 1024;                       // 4*(N_NODE+1)
    unsigned short* edges = (unsigned short*)(off + 4 * (N_NODE + 1));  // 4*NEDGE u16 (4.8 MB)
    bf16* md1     = (bf16*)(edges + (size_t)4 * NEDGE);// 50000*128 bf16; 16B-aligned
    bf16* mg1     = md1 + (size_t)N_NODE * 128;        // B-row i = row (i + N_NODE)
    bf16* hd      = mg1 + (size_t)N_NODE * 128;        // 50000*64 bf16
    bf16* hg      = hd + (size_t)N_NODE * 64;
    int*  order   = (int*)(hg + (size_t)N_NODE * 64);  // 2*N_NODE ints (400 KB)
    bf16* md2     = md1;                               // layer-2 packed (stride 64 bf16)
    bf16* mg2     = md1 + (size_t)N_NODE * 64;
    unsigned* gpart = (unsigned*)md1;                  // 512*CAPB uints, dead before GEMM1

    // ---- CSR build ----
    hipMemsetAsync(gcur, 0, 1024 * sizeof(int), stream);  // gcur + bins (+cursor, overwritten)
    k_part<<<4 * NBLK1, 256, 0, stream>>>(
        dd_dst, dd_src, gd_dst, gd_src, dg_dst, dg_src, gg_dst, gg_src, gcur, gpart);
    k_csr<<<512, 256, 0, stream>>>(gpart, gcur, off, edges);

    // ---- degree-sorted work order (shared by both gathers) ----
    int ogrid = (2 * N_NODE + 511) / 512;
    k_ohist<<<ogrid, 512, 0, stream>>>(off, bins);
    k_oscan<<<1, 64, 0, stream>>>(bins, cursor);
    k_oscat<<<ogrid, 512, 0, stream>>>(off, cursor, order);

    const int* off_dd = off + 0 * (N_NODE + 1);
    const int* off_gd = off + 1 * (N_NODE + 1);
    const int* off_dg = off + 2 * (N_NODE + 1);
    const int* off_gg = off + 3 * (N_NODE + 1);
    const unsigned short* e_dd = edges + (size_t)0 * NEDGE;
    const unsigned short* e_gd = edges + (size_t)1 * NEDGE;
    const unsigned short* e_dg = edges + (size_t)2 * NEDGE;
    const unsigned short* e_gg = edges + (size_t)3 * NEDGE;

    dim3 gemm_grid((N_NODE + 63) / 64, 2);
    int g64_grid = (2 * N_NODE) / 32;          // 3125 blocks (exact)
    int g32_grid = (2 * N_NODE + 63) / 64;     // 1563 blocks

    // ---- layer 1 ----
    k_gemm_pair<128, 128, true><<<gemm_grid, 256, 0, stream>>>(
        xd, xg, W1dd, W1dg, W1gd, W1gg, md1, mg1, N_NODE);
    k_gather64v4<<<g64_grid, 256, 0, stream>>>(
        md1, order,
        off_dd, e_dd, off_gd, e_gd, b1d, hd,
        off_dg, e_dg, off_gg, e_gg, b1g, hg);

    // ---- layer 2 ----
    k_gemm_pair<64, 64, false><<<gemm_grid, 256, 0, stream>>>(
        hd, hg, W2dd, W2dg, W2gd, W2gg, md2, mg2, N_NODE);
    k_gather32v4<<<g32_grid, 256, 0, stream>>>(
        md2, order,
        off_dd, e_dd, off_gd, e_gd, b2d, out,
        off_dg, e_dg, off_gg, e_gg, b2g, out + (size_t)N_NODE * 32);
}

// Round 6
// 345.883 us; speedup vs baseline: 1.0289x; 1.0289x over previous
//
#include <hip/hip_runtime.h>
#include <hip/hip_bf16.h>

#define N_NODE 50000
#define NEDGE  600000
#define NRANGE 128
#define RSZ    391       // ceil(N_NODE / NRANGE); 128*391 = 50048 >= 50000
#define CAPB   6144      // slot capacity per (rel,range): mean 4688 + ~21 sigma
#define CHUNK  4096
#define NBLK1  147       // ceil(NEDGE / CHUNK)
#define GEMM_GX 782      // ceil(N_NODE / 64)

typedef __hip_bfloat16 bf16;
typedef __attribute__((ext_vector_type(8))) short short8;
typedef __attribute__((ext_vector_type(4))) float floatx4;

__device__ __forceinline__ short f2s(float f) {
    bf16 t = __float2bfloat16(f);
    return *(short*)&t;
}
__device__ __forceinline__ unsigned pk2(float lo, float hi) {
    return ((unsigned)(unsigned short)f2s(lo)) | (((unsigned)(unsigned short)f2s(hi)) << 16);
}
__device__ __forceinline__ void acc2(float& a, float& b, unsigned w, float m) {
    a += m * __uint_as_float(w << 16);
    b += m * __uint_as_float(w & 0xFFFF0000u);
}

// rel 0 = dd (dst=drug), 1 = gd (dst=drug), 2 = dg (dst=gene), 3 = gg (dst=gene)
// key packing: (bucket:7 << 25) | (dst_local:9 << 16) | (src:16)

// ---------- fused launch: blocks [0,588) = edge partition, [588,2152) = layer-1 GEMM ----------
// Independent work: partition reads edge lists; GEMM reads x/W1. One launch fills the
// GPU and removes a serial gap. LDS is a union (GEMM needs 32 KB, part ~17.5 KB).
__global__ __launch_bounds__(256) void k_part_gemm(
    // partition args
    const int* __restrict__ d0, const int* __restrict__ s0,
    const int* __restrict__ d1, const int* __restrict__ s1,
    const int* __restrict__ d2, const int* __restrict__ s2,
    const int* __restrict__ d3, const int* __restrict__ s3,
    int* __restrict__ gcur, unsigned* __restrict__ gpart,
    // GEMM args: out(bf16) = X @ [Wa | Wb] for 2 problems (drug, gene)
    const float* __restrict__ X0, const float* __restrict__ X1,
    const float* __restrict__ Wa0, const float* __restrict__ Wb0,
    const float* __restrict__ Wa1, const float* __restrict__ Wb1,
    bf16* __restrict__ out0, bf16* __restrict__ out1)
{
    __shared__ union {
        struct { int hcur[NRANGE]; int delta[NRANGE]; int sc[256]; unsigned buf[CHUNK]; } p;
        short wl[4 * 8 * 512];   // KC*NB*512 = 32 KB
    } u;

    int tid = threadIdx.x;
    if (blockIdx.x < 4 * NBLK1) {
        // ---------------- partition path ----------------
        int bid = blockIdx.x;
        int rel = bid / NBLK1;
        int c   = bid - rel * NBLK1;
        const int* dp = rel == 0 ? d0 : rel == 1 ? d1 : rel == 2 ? d2 : d3;
        const int* sp = rel == 0 ? s0 : rel == 1 ? s1 : rel == 2 ? s2 : s3;
        int e0 = c * CHUNK;
        int e1 = min(e0 + CHUNK, NEDGE);
        int cnt_chunk = e1 - e0;

        if (tid < NRANGE) u.p.hcur[tid] = 0;
        __syncthreads();
        for (int e = e0 + tid; e < e1; e += 256)
            atomicAdd(&u.p.hcur[dp[e] / RSZ], 1);
        __syncthreads();
        int v = (tid < NRANGE) ? u.p.hcur[tid] : 0;
        u.p.sc[tid] = v;
        __syncthreads();
        for (int d = 1; d < NRANGE; d <<= 1) {
            int t = (tid >= d && tid < NRANGE) ? u.p.sc[tid - d] : 0;
            __syncthreads();
            u.p.sc[tid] += t;
            __syncthreads();
        }
        if (tid < NRANGE) {
            int start = u.p.sc[tid] - v;
            int bg    = rel * NRANGE + tid;
            int resv  = atomicAdd(&gcur[bg], v);
            u.p.delta[tid] = bg * CAPB + resv - start;
            u.p.hcur[tid]  = start;
        }
        __syncthreads();
        for (int e = e0 + tid; e < e1; e += 256) {
            int d = dp[e];
            int b = d / RSZ;
            int p = atomicAdd(&u.p.hcur[b], 1);
            u.p.buf[p] = ((unsigned)b << 25) | ((unsigned)(d - b * RSZ) << 16) | (unsigned)sp[e];
        }
        __syncthreads();
        for (int i = tid; i < cnt_chunk; i += 256) {
            unsigned key = u.p.buf[i];
            gpart[u.p.delta[key >> 25] + i] = key;
        }
    } else {
        // ---------------- layer-1 GEMM path (K=128, NOUT=128, fp32 A) ----------------
        constexpr int NB = 8, KC = 4, NH = 64;
        int bid2 = blockIdx.x - 4 * NBLK1;
        int sel  = bid2 >= GEMM_GX;
        int bx   = sel ? bid2 - GEMM_GX : bid2;
        const float* X  = sel ? X1 : X0;
        const float* Wa = sel ? Wa1 : Wa0;
        const float* Wb = sel ? Wb1 : Wb0;
        bf16*       outp = sel ? out1 : out0;

        for (int i = tid; i < KC * NB * 512; i += 256) {
            int j  = i & 7;
            int n  = (i >> 3) & 15;
            int q  = (i >> 7) & 3;
            int nb = (i >> 9) & (NB - 1);
            int kc = i >> 12;
            int k  = kc * 32 + q * 8 + j;
            int c  = nb * 16 + n;
            float w = (c < NH) ? Wa[k * NH + c] : Wb[k * NH + (c - NH)];
            u.wl[i] = f2s(w);
        }
        __syncthreads();

        int lane = tid & 63, wv = tid >> 6;
        int q = lane >> 4, lidx = lane & 15;
        int row0 = bx * 64 + wv * 16;
        int rowA = min(row0 + lidx, N_NODE - 1);

        floatx4 acc[NB];
#pragma unroll
        for (int nb = 0; nb < NB; nb++) acc[nb] = (floatx4){0.f, 0.f, 0.f, 0.f};

#pragma unroll
        for (int kc = 0; kc < KC; kc++) {
            const float* Xf = X + (size_t)rowA * 128 + kc * 32 + q * 8;
            float4 f0 = *(const float4*)Xf;
            float4 f1 = *(const float4*)(Xf + 4);
            short8 a;
            a[0] = f2s(f0.x); a[1] = f2s(f0.y); a[2] = f2s(f0.z); a[3] = f2s(f0.w);
            a[4] = f2s(f1.x); a[5] = f2s(f1.y); a[6] = f2s(f1.z); a[7] = f2s(f1.w);
#pragma unroll
            for (int nb = 0; nb < NB; nb++) {
                short8 b = *(const short8*)&u.wl[((kc * NB + nb) * 64 + lane) * 8];
                acc[nb] = __builtin_amdgcn_mfma_f32_16x16x32_bf16(a, b, acc[nb], 0, 0, 0);
            }
        }
#pragma unroll
        for (int nb = 0; nb < NB; nb++) {
#pragma unroll
            for (int r = 0; r < 4; r++) {
                int row = row0 + q * 4 + r;
                if (row < N_NODE)
                    outp[(size_t)row * 128 + nb * 16 + lidx] = __float2bfloat16(acc[nb][r]);
            }
        }
    }
}

// ---------- per (rel,range) block -> final CSR (off + u16 edges), local base scan ----------
__global__ __launch_bounds__(256) void k_csr(
    const unsigned* __restrict__ gpart, const int* __restrict__ gcnt,
    int* __restrict__ off, unsigned short* __restrict__ edges)
{
    __shared__ int cur[RSZ];
    __shared__ unsigned short stg[CAPB];
    __shared__ int sc[256];
    int bid = blockIdx.x;
    int rel = bid >> 7, r = bid & (NRANGE - 1);
    int tid = threadIdx.x;
    int range0 = r * RSZ;
    int RS = min(RSZ, N_NODE - range0);
    if (RS < 0) RS = 0;
    int count = gcnt[bid];
    size_t slot0 = (size_t)bid * CAPB;

    // local base: exclusive scan of this rel's 128 bucket counts up to r
    int vb = (tid < NRANGE) ? gcnt[rel * NRANGE + tid] : 0;
    sc[tid] = vb;
    __syncthreads();
    for (int d = 1; d < NRANGE; d <<= 1) {
        int t = (tid >= d && tid < NRANGE) ? sc[tid - d] : 0;
        __syncthreads();
        sc[tid] += t;
        __syncthreads();
    }
    int base = (r > 0) ? sc[r - 1] : 0;
    __syncthreads();

    for (int i = tid; i < RSZ; i += 256) cur[i] = 0;
    __syncthreads();
    for (int i = tid; i < count; i += 256)
        atomicAdd(&cur[(gpart[slot0 + i] >> 16) & 0x1FF], 1);
    __syncthreads();
    int vloc[2]; int run = 0;
#pragma unroll
    for (int j = 0; j < 2; j++) {
        int idx = tid * 2 + j;
        int x = (idx < RSZ) ? cur[idx] : 0;
        vloc[j] = x; run += x;
    }
    sc[tid] = run;
    __syncthreads();
    for (int d = 1; d < 256; d <<= 1) {
        int t = (tid >= d) ? sc[tid - d] : 0;
        __syncthreads();
        sc[tid] += t;
        __syncthreads();
    }
    int excl = sc[tid] - run;
    run = excl;
#pragma unroll
    for (int j = 0; j < 2; j++) {
        int idx = tid * 2 + j;
        if (idx < RSZ) { int x = vloc[j]; cur[idx] = run; run += x; }
    }
    __syncthreads();
    for (int i = tid; i < RS; i += 256)
        off[rel * (N_NODE + 1) + range0 + i] = base + cur[i];
    if (r == NRANGE - 1 && tid == 0) off[rel * (N_NODE + 1) + N_NODE] = NEDGE;
    __syncthreads();
    for (int i = tid; i < count; i += 256) {
        unsigned key = gpart[slot0 + i];
        int p = atomicAdd(&cur[(key >> 16) & 0x1FF], 1);
        stg[p] = (unsigned short)(key & 0xFFFFu);
    }
    __syncthreads();
    for (int i = tid; i < count; i += 256)
        edges[(size_t)rel * NEDGE + base + i] = stg[i];
}

// ---------- group-per-node segment accumulate (round-2 proven structure, u16 edges) ----------
template<int ROWU>
__device__ __forceinline__ void seg_run(
    int n, const unsigned short* __restrict__ ep, float sc,
    const unsigned* __restrict__ base, float* s)
{
    int nfull = n & ~3;
    for (int i = 0; i < nfull; i += 4) {
        int e0 = ep[i + 0];
        int e1 = ep[i + 1];
        int e2 = ep[i + 2];
        int e3 = ep[i + 3];
        uint4 w0 = *(const uint4*)(base + e0 * ROWU);
        uint4 w1 = *(const uint4*)(base + e1 * ROWU);
        uint4 w2 = *(const uint4*)(base + e2 * ROWU);
        uint4 w3 = *(const uint4*)(base + e3 * ROWU);
        acc2(s[0], s[1], w0.x, sc); acc2(s[2], s[3], w0.y, sc);
        acc2(s[4], s[5], w0.z, sc); acc2(s[6], s[7], w0.w, sc);
        acc2(s[0], s[1], w1.x, sc); acc2(s[2], s[3], w1.y, sc);
        acc2(s[4], s[5], w1.z, sc); acc2(s[6], s[7], w1.w, sc);
        acc2(s[0], s[1], w2.x, sc); acc2(s[2], s[3], w2.y, sc);
        acc2(s[4], s[5], w2.z, sc); acc2(s[6], s[7], w2.w, sc);
        acc2(s[0], s[1], w3.x, sc); acc2(s[2], s[3], w3.y, sc);
        acc2(s[4], s[5], w3.z, sc); acc2(s[6], s[7], w3.w, sc);
    }
    for (int i = nfull; i < n; i++) {
        int e = ep[i];
        uint4 w = *(const uint4*)(base + e * ROWU);
        acc2(s[0], s[1], w.x, sc); acc2(s[2], s[3], w.y, sc);
        acc2(s[4], s[5], w.z, sc); acc2(s[6], s[7], w.w, sc);
    }
}

// ---------- fused layer-1 gather: 8-lane group per node, 64 feats ----------
// m1 = [md1 rows | mg1 rows] (stride 128 bf16); B-edges via base + N_NODE*64 uints.
// Output h = [hd rows | hg rows] (stride 64 bf16) for layer 2.
__global__ __launch_bounds__(256) void k_gather64v5(
    const bf16* __restrict__ m1,
    const int* __restrict__ offA0, const unsigned short* __restrict__ eA0,
    const int* __restrict__ offB0, const unsigned short* __restrict__ eB0,
    const float* __restrict__ bias0, bf16* __restrict__ out0,
    const int* __restrict__ offA1, const unsigned short* __restrict__ eA1,
    const int* __restrict__ offB1, const unsigned short* __restrict__ eB1,
    const float* __restrict__ bias1, bf16* __restrict__ out1)
{
    int tid  = threadIdx.x;
    int gid  = blockIdx.x * 32 + (tid >> 3);   // grid exact: 3125*32 = 100000
    int lidx = tid & 7;
    int half = (gid >= N_NODE);
    int wid  = gid - (half ? N_NODE : 0);
    const int* offA = half ? offA1 : offA0;
    const unsigned short* eA = half ? eA1 : eA0;
    const int* offB = half ? offB1 : offB0;
    const unsigned short* eB = half ? eB1 : eB0;
    const float* bias = half ? bias1 : bias0;
    bf16* out = half ? out1 : out0;

    const unsigned* base = (const unsigned*)m1 + (half ? 32 : 0) + lidx * 4;

    int begA = offA[wid], nA = offA[wid + 1] - begA;
    int begB = offB[wid], nB = offB[wid + 1] - begB;
    float ia = 1.f / (float)max(nA, 1);
    float ib = 1.f / (float)max(nB, 1);

    float s[8] = {0.f,0.f,0.f,0.f,0.f,0.f,0.f,0.f};
    seg_run<64>(nA, eA + begA, ia, base, s);
    seg_run<64>(nB, eB + begB, ib, base + N_NODE * 64, s);

    float h[8];
#pragma unroll
    for (int k = 0; k < 8; k++)
        h[k] = fmaxf(s[k] + bias[lidx * 8 + k], 0.f);
    uint4 v;
    v.x = pk2(h[0], h[1]); v.y = pk2(h[2], h[3]);
    v.z = pk2(h[4], h[5]); v.w = pk2(h[6], h[7]);
    *(uint4*)(out + (size_t)wid * 64 + lidx * 8) = v;
}

// ---------- fused layer-2: gather full h rows (128 B = one fetch granule, all useful),
// per-relation 64-d mean accumulators, then W2 matvec per node (replaces gemm2 +
// m2 write/read round trip). 8-lane group per node.
__global__ __launch_bounds__(256) void k_gather32ft(
    const bf16* __restrict__ h,                  // [2N][64] bf16, rows 128 B
    const int* __restrict__ off, const unsigned short* __restrict__ edges,
    const float* __restrict__ W2dd, const float* __restrict__ W2gd,
    const float* __restrict__ W2dg, const float* __restrict__ W2gg,
    const float* __restrict__ b2d, const float* __restrict__ b2g,
    float* __restrict__ out)
{
    __shared__ float hb[32][2][66];   // group stride 132 floats -> bank step 4, conflict-free
    int tid  = threadIdx.x;
    int grp  = tid >> 3;
    int lidx = tid & 7;
    int gid  = blockIdx.x * 32 + grp;            // exact: 3125*32 = 100000
    int half = (gid >= N_NODE);
    int wid  = gid - (half ? N_NODE : 0);
    const int* offA = off + (half ? 2 : 0) * (N_NODE + 1);
    const int* offB = off + (half ? 3 : 1) * (N_NODE + 1);
    const unsigned short* eA = edges + (size_t)(half ? 2 : 0) * NEDGE;
    const unsigned short* eB = edges + (size_t)(half ? 3 : 1) * NEDGE;

    const unsigned* base = (const unsigned*)h + lidx * 4;   // full row, ROWU=32

    int begA = offA[wid], nA = offA[wid + 1] - begA;
    int begB = offB[wid], nB = offB[wid + 1] - begB;
    float ia = 1.f / (float)max(nA, 1);
    float ib = 1.f / (float)max(nB, 1);

    float sA[8] = {0.f,0.f,0.f,0.f,0.f,0.f,0.f,0.f};
    float sB[8] = {0.f,0.f,0.f,0.f,0.f,0.f,0.f,0.f};
    seg_run<32>(nA, eA + begA, ia, base, sA);                 // A srcs: drug rows
    seg_run<32>(nB, eB + begB, ib, base + N_NODE * 32, sB);   // B srcs: gene rows

#pragma unroll
    for (int k = 0; k < 8; k++) {
        hb[grp][0][lidx * 8 + k] = sA[k];
        hb[grp][1][lidx * 8 + k] = sB[k];
    }
    __syncthreads();

    // matvec: out[j] = sum_k hbA[k]*Wa[k][j] + hbB[k]*Wb[k][j] + bias[j]; lane owns j in [4*lidx, +4)
    const float* Wa = half ? W2dg : W2dd;
    const float* Wb = half ? W2gg : W2gd;
    const float* bias = half ? b2g : b2d;
    const float* hbA = hb[grp][0];
    const float* hbB = hb[grp][1];
    int j0 = lidx * 4;
    float o0 = 0.f, o1 = 0.f, o2 = 0.f, o3 = 0.f;
#pragma unroll 8
    for (int k = 0; k < 64; k++) {
        float a = hbA[k], b = hbB[k];
        float4 wa = *(const float4*)(Wa + k * 32 + j0);
        float4 wb = *(const float4*)(Wb + k * 32 + j0);
        o0 += a * wa.x + b * wb.x;
        o1 += a * wa.y + b * wb.y;
        o2 += a * wa.z + b * wb.z;
        o3 += a * wa.w + b * wb.w;
    }
    float4 v;
    v.x = o0 + bias[j0 + 0];
    v.y = o1 + bias[j0 + 1];
    v.z = o2 + bias[j0 + 2];
    v.w = o3 + bias[j0 + 3];
    *(float4*)(out + (size_t)gid * 32 + j0) = v;   // rows [0:N)=drug, [N:2N)=gene
}

// ---------------- launcher ----------------
extern "C" void kernel_launch(void* const* d_in, const int* in_sizes, int n_in,
                              void* d_out, int out_size, void* d_ws, size_t ws_size,
                              hipStream_t stream)
{
    const float* xd = (const float*)d_in[0];
    const float* xg = (const float*)d_in[1];
    const int* dd_src = (const int*)d_in[2];  const int* dd_dst = (const int*)d_in[3];
    const int* dg_src = (const int*)d_in[4];  const int* dg_dst = (const int*)d_in[5];
    const int* gd_src = (const int*)d_in[6];  const int* gd_dst = (const int*)d_in[7];
    const int* gg_src = (const int*)d_in[8];  const int* gg_dst = (const int*)d_in[9];
    const float* W1dd = (const float*)d_in[10];
    const float* W1dg = (const float*)d_in[11];
    const float* W1gd = (const float*)d_in[12];
    const float* W1gg = (const float*)d_in[13];
    const float* b1d  = (const float*)d_in[14];
    const float* b1g  = (const float*)d_in[15];
    const float* W2dd = (const float*)d_in[16];
    const float* W2dg = (const float*)d_in[17];
    const float* W2gd = (const float*)d_in[18];
    const float* W2gg = (const float*)d_in[19];
    const float* b2d  = (const float*)d_in[20];
    const float* b2g  = (const float*)d_in[21];
    float* out = (float*)d_out;

    // workspace layout
    int* gcur     = (int*)d_ws;                        // 512 ints
    int* off      = gcur + 512;                        // 4*(N_NODE+1)
    unsigned short* edges = (unsigned short*)(off + 4 * (N_NODE + 1));  // 4*NEDGE u16 (4.8 MB)
    bf16* md1     = (bf16*)(edges + (size_t)4 * NEDGE);// [md1|mg1]: 2*50000*128 bf16 (25.6 MB)
    bf16* mg1     = md1 + (size_t)N_NODE * 128;
    bf16* h       = mg1 + (size_t)N_NODE * 128;        // [hd|hg]: 2*50000*64 bf16 (12.8 MB)
    unsigned* gpart = (unsigned*)h;                    // 512*CAPB uints (12.58 MB) aliases h:
                                                       // dead after k_csr, before gather64 writes h.
                                                       // (md1 must NOT alias gpart: GEMM runs || part.)

    // ---- stage 1: edge partition || layer-1 GEMM (independent, one launch) ----
    hipMemsetAsync(gcur, 0, 512 * sizeof(int), stream);
    k_part_gemm<<<4 * NBLK1 + 2 * GEMM_GX, 256, 0, stream>>>(
        dd_dst, dd_src, gd_dst, gd_src, dg_dst, dg_src, gg_dst, gg_src, gcur, gpart,
        xd, xg, W1dd, W1dg, W1gd, W1gg, md1, mg1);

    // ---- stage 2: CSR finalize ----
    k_csr<<<512, 256, 0, stream>>>(gpart, gcur, off, edges);

    const int* off_dd = off + 0 * (N_NODE + 1);
    const int* off_gd = off + 1 * (N_NODE + 1);
    const int* off_dg = off + 2 * (N_NODE + 1);
    const int* off_gg = off + 3 * (N_NODE + 1);
    const unsigned short* e_dd = edges + (size_t)0 * NEDGE;
    const unsigned short* e_gd = edges + (size_t)1 * NEDGE;
    const unsigned short* e_dg = edges + (size_t)2 * NEDGE;
    const unsigned short* e_gg = edges + (size_t)3 * NEDGE;

    int g_grid = (2 * N_NODE) / 32;   // 3125 blocks exact, both gathers

    // ---- stage 3: layer-1 gather -> h ----
    k_gather64v5<<<g_grid, 256, 0, stream>>>(
        md1,
        off_dd, e_dd, off_gd, e_gd, b1d, h,
        off_dg, e_dg, off_gg, e_gg, b1g, h + (size_t)N_NODE * 64);

    // ---- stage 4: layer-2 gather + fused W2 transform -> out ----
    k_gather32ft<<<g_grid, 256, 0, stream>>>(
        h, off, edges, W2dd, W2gd, W2dg, W2gg, b2d, b2g, out);
}

// Round 7
// 295.946 us; speedup vs baseline: 1.2025x; 1.1687x over previous
//
#include <hip/hip_runtime.h>
#include <hip/hip_bf16.h>

#define N_NODE 50000
#define NEDGE  600000
#define NRANGE 128
#define RSZ    391       // ceil(N_NODE / NRANGE); 128*391 = 50048 >= 50000
#define CAPB   6144      // slot capacity per (rel,range): mean 4688 + ~21 sigma
#define CHUNK  4096
#define NBLK1  147       // ceil(NEDGE / CHUNK); last chunk = 2384 (divisible by 4)
#define GEMM_GX 391      // ceil(N_NODE / 128): 8-wave GEMM blocks

typedef __hip_bfloat16 bf16;
typedef __attribute__((ext_vector_type(8))) short short8;
typedef __attribute__((ext_vector_type(4))) float floatx4;

__device__ __forceinline__ short f2s(float f) {
    bf16 t = __float2bfloat16(f);
    return *(short*)&t;
}
__device__ __forceinline__ unsigned pk2(float lo, float hi) {
    return ((unsigned)(unsigned short)f2s(lo)) | (((unsigned)(unsigned short)f2s(hi)) << 16);
}
__device__ __forceinline__ void acc2(float& a, float& b, unsigned w, float m) {
    a += m * __uint_as_float(w << 16);
    b += m * __uint_as_float(w & 0xFFFF0000u);
}

// rel 0 = dd (dst=drug), 1 = gd (dst=drug), 2 = dg (dst=gene), 3 = gg (dst=gene)
// key packing: (bucket:7 << 25) | (dst_local:9 << 16) | (src:16)

// ---------- fused launch (512 thr): blocks [0,588) = edge partition, [588,1370) = layer-1 GEMM ----------
// Vectorized int4 edge loads (4 iters/pass instead of 16) + 8 waves/block for latency hiding.
__global__ __launch_bounds__(512) void k_part_gemm(
    const int* __restrict__ d0, const int* __restrict__ s0,
    const int* __restrict__ d1, const int* __restrict__ s1,
    const int* __restrict__ d2, const int* __restrict__ s2,
    const int* __restrict__ d3, const int* __restrict__ s3,
    int* __restrict__ gcur, unsigned* __restrict__ gpart,
    const float* __restrict__ X0, const float* __restrict__ X1,
    const float* __restrict__ Wa0, const float* __restrict__ Wb0,
    const float* __restrict__ Wa1, const float* __restrict__ Wb1,
    bf16* __restrict__ out0, bf16* __restrict__ out1)
{
    __shared__ union {
        struct { unsigned buf[CHUNK]; int sc[512]; int hcur[NRANGE]; int delta[NRANGE]; } p;
        short wl[4 * 8 * 512];   // 32 KB
    } u;

    int tid = threadIdx.x;
    if (blockIdx.x < 4 * NBLK1) {
        // ---------------- partition path ----------------
        int bid = blockIdx.x;
        int rel = bid / NBLK1;
        int c   = bid - rel * NBLK1;
        const int* dp = rel == 0 ? d0 : rel == 1 ? d1 : rel == 2 ? d2 : d3;
        const int* sp = rel == 0 ? s0 : rel == 1 ? s1 : rel == 2 ? s2 : s3;
        int e0 = c * CHUNK;
        int e1 = min(e0 + CHUNK, NEDGE);
        int cnt = e1 - e0;                 // 4096 or 2384; both divisible by 4
        const int4* dp4 = (const int4*)(dp + e0);
        const int4* sp4 = (const int4*)(sp + e0);
        int nv = cnt >> 2;

        if (tid < NRANGE) u.p.hcur[tid] = 0;
        __syncthreads();
        // pass 1: bucket counts (int4 loads)
        for (int i = tid; i < nv; i += 512) {
            int4 d = dp4[i];
            atomicAdd(&u.p.hcur[d.x / RSZ], 1);
            atomicAdd(&u.p.hcur[d.y / RSZ], 1);
            atomicAdd(&u.p.hcur[d.z / RSZ], 1);
            atomicAdd(&u.p.hcur[d.w / RSZ], 1);
        }
        __syncthreads();
        int v = (tid < NRANGE) ? u.p.hcur[tid] : 0;
        u.p.sc[tid] = v;
        __syncthreads();
        for (int d = 1; d < NRANGE; d <<= 1) {
            int t = (tid >= d && tid < NRANGE) ? u.p.sc[tid - d] : 0;
            __syncthreads();
            if (tid < NRANGE) u.p.sc[tid] += t;
            __syncthreads();
        }
        if (tid < NRANGE) {
            int start = u.p.sc[tid] - v;
            int bg    = rel * NRANGE + tid;
            int resv  = atomicAdd(&gcur[bg], v);
            u.p.delta[tid] = bg * CAPB + resv - start;
            u.p.hcur[tid]  = start;
        }
        __syncthreads();
        // pass 2: fill buf bucketed (int4 loads)
        for (int i = tid; i < nv; i += 512) {
            int4 d = dp4[i];
            int4 s = sp4[i];
#define PUT(dd, ss) { int b = (dd) / RSZ; int p = atomicAdd(&u.p.hcur[b], 1); \
                      u.p.buf[p] = ((unsigned)b << 25) | ((unsigned)((dd) - b * RSZ) << 16) | (unsigned)(ss); }
            PUT(d.x, s.x) PUT(d.y, s.y) PUT(d.z, s.z) PUT(d.w, s.w)
#undef PUT
        }
        __syncthreads();
        // pass 3: scatter to global slots (uint4 LDS reads, 4 independent stores)
        for (int i = tid * 4; i < cnt; i += 2048) {
            uint4 kb = *(const uint4*)&u.p.buf[i];
            gpart[u.p.delta[kb.x >> 25] + i + 0] = kb.x;
            gpart[u.p.delta[kb.y >> 25] + i + 1] = kb.y;
            gpart[u.p.delta[kb.z >> 25] + i + 2] = kb.z;
            gpart[u.p.delta[kb.w >> 25] + i + 3] = kb.w;
        }
    } else {
        // ---------------- layer-1 GEMM path (K=128, NOUT=128, fp32 A), 8 waves ----------------
        constexpr int NB = 8, KC = 4, NH = 64;
        int bid2 = blockIdx.x - 4 * NBLK1;
        int sel  = bid2 >= GEMM_GX;
        int bx   = sel ? bid2 - GEMM_GX : bid2;
        const float* X  = sel ? X1 : X0;
        const float* Wa = sel ? Wa1 : Wa0;
        const float* Wb = sel ? Wb1 : Wb0;
        bf16*       outp = sel ? out1 : out0;

        for (int i = tid; i < KC * NB * 512; i += 512) {
            int j  = i & 7;
            int n  = (i >> 3) & 15;
            int q  = (i >> 7) & 3;
            int nb = (i >> 9) & (NB - 1);
            int kc = i >> 12;
            int k  = kc * 32 + q * 8 + j;
            int c  = nb * 16 + n;
            float w = (c < NH) ? Wa[k * NH + c] : Wb[k * NH + (c - NH)];
            u.wl[i] = f2s(w);
        }
        __syncthreads();

        int lane = tid & 63, wv = tid >> 6;        // wv in [0,8)
        int q = lane >> 4, lidx = lane & 15;
        int row0 = bx * 128 + wv * 16;
        int rowA = min(row0 + lidx, N_NODE - 1);

        floatx4 acc[NB];
#pragma unroll
        for (int nb = 0; nb < NB; nb++) acc[nb] = (floatx4){0.f, 0.f, 0.f, 0.f};

#pragma unroll
        for (int kc = 0; kc < KC; kc++) {
            const float* Xf = X + (size_t)rowA * 128 + kc * 32 + q * 8;
            float4 f0 = *(const float4*)Xf;
            float4 f1 = *(const float4*)(Xf + 4);
            short8 a;
            a[0] = f2s(f0.x); a[1] = f2s(f0.y); a[2] = f2s(f0.z); a[3] = f2s(f0.w);
            a[4] = f2s(f1.x); a[5] = f2s(f1.y); a[6] = f2s(f1.z); a[7] = f2s(f1.w);
#pragma unroll
            for (int nb = 0; nb < NB; nb++) {
                short8 b = *(const short8*)&u.wl[((kc * NB + nb) * 64 + lane) * 8];
                acc[nb] = __builtin_amdgcn_mfma_f32_16x16x32_bf16(a, b, acc[nb], 0, 0, 0);
            }
        }
#pragma unroll
        for (int nb = 0; nb < NB; nb++) {
#pragma unroll
            for (int r = 0; r < 4; r++) {
                int row = row0 + q * 4 + r;
                if (row < N_NODE)
                    outp[(size_t)row * 128 + nb * 16 + lidx] = __float2bfloat16(acc[nb][r]);
            }
        }
    }
}

// ---------- per (rel,range) block -> final CSR (512 thr, uint4 loads, local base scan) ----------
__global__ __launch_bounds__(512) void k_csr(
    const unsigned* __restrict__ gpart, const int* __restrict__ gcnt,
    int* __restrict__ off, unsigned short* __restrict__ edges)
{
    __shared__ unsigned short stg[CAPB];   // first: 16B-aligned
    __shared__ int cur[RSZ];
    __shared__ int sc[512];
    int bid = blockIdx.x;
    int rel = bid >> 7, r = bid & (NRANGE - 1);
    int tid = threadIdx.x;
    int range0 = r * RSZ;
    int RS = min(RSZ, N_NODE - range0);
    if (RS < 0) RS = 0;
    int count = gcnt[bid];
    const uint4* gp4 = (const uint4*)(gpart + (size_t)bid * CAPB);
    const unsigned* gp = gpart + (size_t)bid * CAPB;
    int count4 = count & ~3;

    // local base: exclusive scan of this rel's 128 bucket counts up to r
    int vb = (tid < NRANGE) ? gcnt[rel * NRANGE + tid] : 0;
    sc[tid] = vb;
    __syncthreads();
    for (int d = 1; d < NRANGE; d <<= 1) {
        int t = (tid >= d && tid < NRANGE) ? sc[tid - d] : 0;
        __syncthreads();
        if (tid < NRANGE) sc[tid] += t;
        __syncthreads();
    }
    int base = (r > 0) ? sc[r - 1] : 0;
    __syncthreads();

    for (int i = tid; i < RSZ; i += 512) cur[i] = 0;
    __syncthreads();
    // hist (uint4)
    for (int i = tid * 4; i < count4; i += 2048) {
        uint4 g = gp4[i >> 2];
        atomicAdd(&cur[(g.x >> 16) & 0x1FF], 1);
        atomicAdd(&cur[(g.y >> 16) & 0x1FF], 1);
        atomicAdd(&cur[(g.z >> 16) & 0x1FF], 1);
        atomicAdd(&cur[(g.w >> 16) & 0x1FF], 1);
    }
    if (tid < (count & 3))
        atomicAdd(&cur[(gp[count4 + tid] >> 16) & 0x1FF], 1);
    __syncthreads();
    // exclusive scan of cur[0..RSZ), one slot per thread
    int x = (tid < RSZ) ? cur[tid] : 0;
    sc[tid] = x;
    __syncthreads();
    for (int d = 1; d < 512; d <<= 1) {
        int t = (tid >= d) ? sc[tid - d] : 0;
        __syncthreads();
        sc[tid] += t;
        __syncthreads();
    }
    int excl = sc[tid] - x;
    __syncthreads();
    if (tid < RSZ) cur[tid] = excl;
    __syncthreads();
    for (int i = tid; i < RS; i += 512)
        off[rel * (N_NODE + 1) + range0 + i] = base + cur[i];
    if (r == NRANGE - 1 && tid == 0) off[rel * (N_NODE + 1) + N_NODE] = NEDGE;
    __syncthreads();
    // scatter to stg (uint4)
    for (int i = tid * 4; i < count4; i += 2048) {
        uint4 g = gp4[i >> 2];
#define SCAT(gg) { int p = atomicAdd(&cur[((gg) >> 16) & 0x1FF], 1); stg[p] = (unsigned short)((gg) & 0xFFFFu); }
        SCAT(g.x) SCAT(g.y) SCAT(g.z) SCAT(g.w)
#undef SCAT
    }
    if (tid < (count & 3)) {
        unsigned g = gp[count4 + tid];
        int p = atomicAdd(&cur[(g >> 16) & 0x1FF], 1);
        stg[p] = (unsigned short)(g & 0xFFFFu);
    }
    __syncthreads();
    for (int i = tid; i < count; i += 512)
        edges[(size_t)rel * NEDGE + base + i] = stg[i];
}

// ---------- MFMA dual-weight GEMM pair (layer 2): out(bf16) = X @ [Wa | Wb] ----------
template <int K, int NOUT, bool AFP32>
__global__ __launch_bounds__(256) void k_gemm_pair(
    const void* __restrict__ X0, const void* __restrict__ X1,
    const float* __restrict__ Wa0, const float* __restrict__ Wb0,
    const float* __restrict__ Wa1, const float* __restrict__ Wb1,
    bf16* __restrict__ out0, bf16* __restrict__ out1, int M)
{
    constexpr int NB  = NOUT / 16;
    constexpr int KC  = K / 32;
    constexpr int NH  = NOUT / 2;
    constexpr int NBL = (NB == 8) ? 3 : 2;
    __shared__ short Wl[KC * NB * 512];

    int sel = blockIdx.y;
    const void*  X  = sel ? X1 : X0;
    const float* Wa = sel ? Wa1 : Wa0;
    const float* Wb = sel ? Wb1 : Wb0;
    bf16*        out = sel ? out1 : out0;

    int tid = threadIdx.x;
    for (int i = tid; i < KC * NB * 512; i += 256) {
        int j  = i & 7;
        int n  = (i >> 3) & 15;
        int q  = (i >> 7) & 3;
        int nb = (i >> 9) & (NB - 1);
        int kc = i >> (9 + NBL);
        int k  = kc * 32 + q * 8 + j;
        int c  = nb * 16 + n;
        float w = (c < NH) ? Wa[k * NH + c] : Wb[k * NH + (c - NH)];
        Wl[i] = f2s(w);
    }
    __syncthreads();

    int lane = tid & 63, wv = tid >> 6;
    int q = lane >> 4, lidx = lane & 15;
    int row0 = blockIdx.x * 64 + wv * 16;
    int rowA = min(row0 + lidx, M - 1);

    floatx4 acc[NB];
#pragma unroll
    for (int nb = 0; nb < NB; nb++) acc[nb] = (floatx4){0.f, 0.f, 0.f, 0.f};

#pragma unroll
    for (int kc = 0; kc < KC; kc++) {
        short8 a;
        if constexpr (AFP32) {
            const float* Xf = (const float*)X + (size_t)rowA * K + kc * 32 + q * 8;
            float4 f0 = *(const float4*)Xf;
            float4 f1 = *(const float4*)(Xf + 4);
            a[0] = f2s(f0.x); a[1] = f2s(f0.y); a[2] = f2s(f0.z); a[3] = f2s(f0.w);
            a[4] = f2s(f1.x); a[5] = f2s(f1.y); a[6] = f2s(f1.z); a[7] = f2s(f1.w);
        } else {
            a = *(const short8*)((const short*)X + (size_t)rowA * K + kc * 32 + q * 8);
        }
#pragma unroll
        for (int nb = 0; nb < NB; nb++) {
            short8 b = *(const short8*)&Wl[((kc * NB + nb) * 64 + lane) * 8];
            acc[nb] = __builtin_amdgcn_mfma_f32_16x16x32_bf16(a, b, acc[nb], 0, 0, 0);
        }
    }
#pragma unroll
    for (int nb = 0; nb < NB; nb++) {
#pragma unroll
        for (int r = 0; r < 4; r++) {
            int row = row0 + q * 4 + r;
            if (row < M)
                out[(size_t)row * NOUT + nb * 16 + lidx] = __float2bfloat16(acc[nb][r]);
        }
    }
}

// ---------- group-per-node segment accumulate (round-2 proven structure, u16 edges) ----------
template<int ROWU>
__device__ __forceinline__ void seg_run(
    int n, const unsigned short* __restrict__ ep, float sc,
    const unsigned* __restrict__ base, float* s)
{
    int nfull = n & ~3;
    for (int i = 0; i < nfull; i += 4) {
        int e0 = ep[i + 0];
        int e1 = ep[i + 1];
        int e2 = ep[i + 2];
        int e3 = ep[i + 3];
        uint4 w0 = *(const uint4*)(base + e0 * ROWU);
        uint4 w1 = *(const uint4*)(base + e1 * ROWU);
        uint4 w2 = *(const uint4*)(base + e2 * ROWU);
        uint4 w3 = *(const uint4*)(base + e3 * ROWU);
        acc2(s[0], s[1], w0.x, sc); acc2(s[2], s[3], w0.y, sc);
        acc2(s[4], s[5], w0.z, sc); acc2(s[6], s[7], w0.w, sc);
        acc2(s[0], s[1], w1.x, sc); acc2(s[2], s[3], w1.y, sc);
        acc2(s[4], s[5], w1.z, sc); acc2(s[6], s[7], w1.w, sc);
        acc2(s[0], s[1], w2.x, sc); acc2(s[2], s[3], w2.y, sc);
        acc2(s[4], s[5], w2.z, sc); acc2(s[6], s[7], w2.w, sc);
        acc2(s[0], s[1], w3.x, sc); acc2(s[2], s[3], w3.y, sc);
        acc2(s[4], s[5], w3.z, sc); acc2(s[6], s[7], w3.w, sc);
    }
    for (int i = nfull; i < n; i++) {
        int e = ep[i];
        uint4 w = *(const uint4*)(base + e * ROWU);
        acc2(s[0], s[1], w.x, sc); acc2(s[2], s[3], w.y, sc);
        acc2(s[4], s[5], w.z, sc); acc2(s[6], s[7], w.w, sc);
    }
}

// ---------- fused layer-1 gather: 8-lane group per node, 64 feats ----------
__global__ __launch_bounds__(256) void k_gather64v5(
    const bf16* __restrict__ m1,
    const int* __restrict__ offA0, const unsigned short* __restrict__ eA0,
    const int* __restrict__ offB0, const unsigned short* __restrict__ eB0,
    const float* __restrict__ bias0, bf16* __restrict__ out0,
    const int* __restrict__ offA1, const unsigned short* __restrict__ eA1,
    const int* __restrict__ offB1, const unsigned short* __restrict__ eB1,
    const float* __restrict__ bias1, bf16* __restrict__ out1)
{
    int tid  = threadIdx.x;
    int gid  = blockIdx.x * 32 + (tid >> 3);   // grid exact: 3125*32 = 100000
    int lidx = tid & 7;
    int half = (gid >= N_NODE);
    int wid  = gid - (half ? N_NODE : 0);
    const int* offA = half ? offA1 : offA0;
    const unsigned short* eA = half ? eA1 : eA0;
    const int* offB = half ? offB1 : offB0;
    const unsigned short* eB = half ? eB1 : eB0;
    const float* bias = half ? bias1 : bias0;
    bf16* out = half ? out1 : out0;

    const unsigned* base = (const unsigned*)m1 + (half ? 32 : 0) + lidx * 4;

    int begA = offA[wid], nA = offA[wid + 1] - begA;
    int begB = offB[wid], nB = offB[wid + 1] - begB;
    float ia = 1.f / (float)max(nA, 1);
    float ib = 1.f / (float)max(nB, 1);

    float s[8] = {0.f,0.f,0.f,0.f,0.f,0.f,0.f,0.f};
    seg_run<64>(nA, eA + begA, ia, base, s);
    seg_run<64>(nB, eB + begB, ib, base + N_NODE * 64, s);

    float h[8];
#pragma unroll
    for (int k = 0; k < 8; k++)
        h[k] = fmaxf(s[k] + bias[lidx * 8 + k], 0.f);
    uint4 v;
    v.x = pk2(h[0], h[1]); v.y = pk2(h[2], h[3]);
    v.z = pk2(h[4], h[5]); v.w = pk2(h[6], h[7]);
    *(uint4*)(out + (size_t)wid * 64 + lidx * 8) = v;
}

// ---------- fused layer-2 gather: 4-lane group per node, 32 feats, f32 out ----------
// m2 = [md2 rows | mg2 rows] contiguous (stride 32 uints); B-edges via base + N_NODE*32.
__global__ __launch_bounds__(256) void k_gather32v2(
    const bf16* __restrict__ m2,
    const int* __restrict__ offA0, const unsigned short* __restrict__ eA0,
    const int* __restrict__ offB0, const unsigned short* __restrict__ eB0,
    const float* __restrict__ bias0, float* __restrict__ out0,
    const int* __restrict__ offA1, const unsigned short* __restrict__ eA1,
    const int* __restrict__ offB1, const unsigned short* __restrict__ eB1,
    const float* __restrict__ bias1, float* __restrict__ out1)
{
    int tid  = threadIdx.x;
    int gid  = blockIdx.x * 64 + (tid >> 2);
    int lidx = tid & 3;
    if (gid >= 2 * N_NODE) return;
    int half = (gid >= N_NODE);
    int wid  = gid - (half ? N_NODE : 0);
    const int* offA = half ? offA1 : offA0;
    const unsigned short* eA = half ? eA1 : eA0;
    const int* offB = half ? offB1 : offB0;
    const unsigned short* eB = half ? eB1 : eB0;
    const float* bias = half ? bias1 : bias0;
    float* out = half ? out1 : out0;

    const unsigned* base = (const unsigned*)m2 + (half ? 16 : 0) + lidx * 4;

    int begA = offA[wid], nA = offA[wid + 1] - begA;
    int begB = offB[wid], nB = offB[wid + 1] - begB;
    float ia = 1.f / (float)max(nA, 1);
    float ib = 1.f / (float)max(nB, 1);

    float s[8] = {0.f,0.f,0.f,0.f,0.f,0.f,0.f,0.f};
    seg_run<32>(nA, eA + begA, ia, base, s);
    seg_run<32>(nB, eB + begB, ib, base + N_NODE * 32, s);

    float* o = out + (size_t)wid * 32 + lidx * 8;
    float4 v0, v1;
    v0.x = s[0] + bias[lidx * 8 + 0];
    v0.y = s[1] + bias[lidx * 8 + 1];
    v0.z = s[2] + bias[lidx * 8 + 2];
    v0.w = s[3] + bias[lidx * 8 + 3];
    v1.x = s[4] + bias[lidx * 8 + 4];
    v1.y = s[5] + bias[lidx * 8 + 5];
    v1.z = s[6] + bias[lidx * 8 + 6];
    v1.w = s[7] + bias[lidx * 8 + 7];
    *(float4*)o = v0;
    *(float4*)(o + 4) = v1;
}

// ---------------- launcher ----------------
extern "C" void kernel_launch(void* const* d_in, const int* in_sizes, int n_in,
                              void* d_out, int out_size, void* d_ws, size_t ws_size,
                              hipStream_t stream)
{
    const float* xd = (const float*)d_in[0];
    const float* xg = (const float*)d_in[1];
    const int* dd_src = (const int*)d_in[2];  const int* dd_dst = (const int*)d_in[3];
    const int* dg_src = (const int*)d_in[4];  const int* dg_dst = (const int*)d_in[5];
    const int* gd_src = (const int*)d_in[6];  const int* gd_dst = (const int*)d_in[7];
    const int* gg_src = (const int*)d_in[8];  const int* gg_dst = (const int*)d_in[9];
    const float* W1dd = (const float*)d_in[10];
    const float* W1dg = (const float*)d_in[11];
    const float* W1gd = (const float*)d_in[12];
    const float* W1gg = (const float*)d_in[13];
    const float* b1d  = (const float*)d_in[14];
    const float* b1g  = (const float*)d_in[15];
    const float* W2dd = (const float*)d_in[16];
    const float* W2dg = (const float*)d_in[17];
    const float* W2gd = (const float*)d_in[18];
    const float* W2gg = (const float*)d_in[19];
    const float* b2d  = (const float*)d_in[20];
    const float* b2g  = (const float*)d_in[21];
    float* out = (float*)d_out;

    // workspace layout
    int* gcur     = (int*)d_ws;                        // 512 ints
    int* off      = gcur + 512;                        // 4*(N_NODE+1)
    unsigned short* edges = (unsigned short*)(off + 4 * (N_NODE + 1));  // 4*NEDGE u16 (4.8 MB)
    bf16* md1     = (bf16*)(edges + (size_t)4 * NEDGE);// [md1|mg1]: 2*50000*128 bf16 (25.6 MB)
    bf16* mg1     = md1 + (size_t)N_NODE * 128;
    bf16* h       = mg1 + (size_t)N_NODE * 128;        // [hd|hg]: 2*50000*64 bf16 (12.8 MB)
    bf16* hd      = h;
    bf16* hg      = h + (size_t)N_NODE * 64;
    bf16* md2     = md1;                               // layer-2 out packed (stride 64 bf16)
    bf16* mg2     = md1 + (size_t)N_NODE * 64;         // B-row i = row (i + N_NODE)
    unsigned* gpart = (unsigned*)h;                    // 512*CAPB uints (12.58 MB) aliases h:
                                                       // dead after k_csr, before gather64 writes h.
                                                       // (md1 must NOT alias gpart: GEMM runs || part.)

    // ---- stage 1: edge partition || layer-1 GEMM (one 512-thread launch) ----
    hipMemsetAsync(gcur, 0, 512 * sizeof(int), stream);
    k_part_gemm<<<4 * NBLK1 + 2 * GEMM_GX, 512, 0, stream>>>(
        dd_dst, dd_src, gd_dst, gd_src, dg_dst, dg_src, gg_dst, gg_src, gcur, gpart,
        xd, xg, W1dd, W1dg, W1gd, W1gg, md1, mg1);

    // ---- stage 2: CSR finalize (512 threads, vectorized) ----
    k_csr<<<512, 512, 0, stream>>>(gpart, gcur, off, edges);

    const int* off_dd = off + 0 * (N_NODE + 1);
    const int* off_gd = off + 1 * (N_NODE + 1);
    const int* off_dg = off + 2 * (N_NODE + 1);
    const int* off_gg = off + 3 * (N_NODE + 1);
    const unsigned short* e_dd = edges + (size_t)0 * NEDGE;
    const unsigned short* e_gd = edges + (size_t)1 * NEDGE;
    const unsigned short* e_dg = edges + (size_t)2 * NEDGE;
    const unsigned short* e_gg = edges + (size_t)3 * NEDGE;

    int g64_grid = (2 * N_NODE) / 32;          // 3125 blocks exact
    int g32_grid = (2 * N_NODE + 63) / 64;     // 1563 blocks
    dim3 gemm2_grid((N_NODE + 63) / 64, 2);

    // ---- stage 3: layer-1 gather -> h ----
    k_gather64v5<<<g64_grid, 256, 0, stream>>>(
        md1,
        off_dd, e_dd, off_gd, e_gd, b1d, hd,
        off_dg, e_dg, off_gg, e_gg, b1g, hg);

    // ---- stage 4: layer-2 GEMM (md1 region is dead now) ----
    k_gemm_pair<64, 64, false><<<gemm2_grid, 256, 0, stream>>>(
        hd, hg, W2dd, W2dg, W2gd, W2gg, md2, mg2, N_NODE);

    // ---- stage 5: layer-2 gather -> out ----
    k_gather32v2<<<g32_grid, 256, 0, stream>>>(
        md2,
        off_dd, e_dd, off_gd, e_gd, b2d, out,
        off_dg, e_dg, off_gg, e_gg, b2g, out + (size_t)N_NODE * 32);
}